// Round 3
// baseline (536.945 us; speedup 1.0000x reference)
//
#include <hip/hip_runtime.h>
#include <hip/hip_bf16.h>

// ---------------------------------------------------------------------------
// SparseCausalSelfAttention: B=2,T=2048,E=2048,NH=16,HS=128.
// I/O float32; internal bf16 MFMA, fp32 acc. Mask = fixed (t%2==0) interleave.
//
// ws plan (peak 96 MiB):
//   [ 0,48M) QKVall (B*T,6144) -> later Yb [0,16M), WPT_A [16,24M), WPT_B [24,32M)
//   [48,56M) XA ; [56,64M) XB  -> later Qb [48,64M)
//   [64,88M) WQT               -> later Kb [64,80M), Vtb [80,96M)
//
// GEMMs: 256x256 tile, BK=64, 8 waves (2Mx4N), 8-phase counted-vmcnt schedule.
// Attn: BQ=128, 4 waves x 32 q-rows (K/V fragments amortized 2x), paired
// q-tiles, 1 block/CU, double-buffered K/V + counted vmcnt, defer-max softmax.
// ---------------------------------------------------------------------------

typedef __attribute__((ext_vector_type(8))) short v8s;   // 8 bf16 (4 VGPRs)
typedef __attribute__((ext_vector_type(4))) float v4f;   // MFMA accumulator

#define GL2LDS(gptr, lptr)                                              \
  __builtin_amdgcn_global_load_lds(                                     \
      (const __attribute__((address_space(1))) void*)(gptr),            \
      (__attribute__((address_space(3))) void*)(lptr), 16, 0, 0)

#define S_BARRIER() asm volatile("s_barrier" ::: "memory")

__device__ __forceinline__ float b2f(unsigned short u) {
  return __uint_as_float(((unsigned int)u) << 16);
}
__device__ __forceinline__ unsigned short f2bf(float f) {
  unsigned int u = __float_as_uint(f);
  u += 0x7fffu + ((u >> 16) & 1u);   // RNE
  return (unsigned short)(u >> 16);
}

// ---------------------------------------------------------------------------
// Both x streams -> bf16 in one launch (XA,XB contiguous in ws).
// ---------------------------------------------------------------------------
__global__ __launch_bounds__(256) void f32_to_bf16_2(
    const float4* __restrict__ a, const float4* __restrict__ b,
    uint2* __restrict__ out, int n4each) {
  int i = blockIdx.x * 256 + threadIdx.x;
  if (i >= 2 * n4each) return;
  float4 v = (i < n4each) ? a[i] : b[i - n4each];
  uint2 o;
  o.x = (unsigned int)f2bf(v.x) | ((unsigned int)f2bf(v.y) << 16);
  o.y = (unsigned int)f2bf(v.z) | ((unsigned int)f2bf(v.w) << 16);
  out[i] = o;
}

// ---------------------------------------------------------------------------
// Transpose f32 (R x C) -> bf16 (C x R); z selects (in0->out0)/(in1->out1).
// ---------------------------------------------------------------------------
__global__ __launch_bounds__(256) void transpose_f32_bf16(
    const float* __restrict__ in0, const float* __restrict__ in1,
    unsigned short* __restrict__ out0, unsigned short* __restrict__ out1,
    int R, int C) {
  const float* in = blockIdx.z ? in1 : in0;
  unsigned short* out = blockIdx.z ? out1 : out0;
  __shared__ unsigned short tile[64][65];
  const int bc = blockIdx.x * 64, br = blockIdx.y * 64;
  const int c  = threadIdx.x & 63;
  const int r0 = threadIdx.x >> 6;
  for (int r = r0; r < 64; r += 4)
    tile[r][c] = f2bf(in[(size_t)(br + r) * C + bc + c]);
  __syncthreads();
  for (int rr = r0; rr < 64; rr += 4)
    out[(size_t)(bc + rr) * R + br + c] = tile[c][rr];
}

// ---------------------------------------------------------------------------
// 256x256-tile GEMM helpers.
// ---------------------------------------------------------------------------
template <int MH, int NH>
__device__ __forceinline__ void mfma_quad(v4f (&acc)[8][4], const v8s (&a)[4][2],
                                          const v8s (&b)[4][2]) {
  __builtin_amdgcn_s_setprio(1);
#pragma unroll
  for (int ks = 0; ks < 2; ++ks)
#pragma unroll
    for (int i = 0; i < 4; ++i)
#pragma unroll
      for (int j = 0; j < 2; ++j)
        acc[MH * 4 + i][NH * 2 + j] = __builtin_amdgcn_mfma_f32_16x16x32_bf16(
            a[i][ks], b[NH * 2 + j][ks], acc[MH * 4 + i][NH * 2 + j], 0, 0, 0);
  __builtin_amdgcn_s_setprio(0);
}

__device__ __forceinline__ void read_a_half(const unsigned short* lds, int base,
                                            int mh, int r, int c0, int c1,
                                            v8s (&a)[4][2]) {
#pragma unroll
  for (int i = 0; i < 4; ++i) {
    const unsigned short* ap = lds + base + (mh * 64 + i * 16 + r) * 64;
    a[i][0] = *(const v8s*)(ap + c0);
    a[i][1] = *(const v8s*)(ap + c1);
  }
}

template <int NH>
__device__ __forceinline__ void read_b_half(const unsigned short* lds, int base,
                                            int brow, int r, int c0, int c1,
                                            v8s (&b)[4][2]) {
#pragma unroll
  for (int j = 0; j < 2; ++j) {
    const unsigned short* bp = lds + base + (brow + (NH * 2 + j) * 16 + r) * 64;
    b[NH * 2 + j][0] = *(const v8s*)(bp + c0);
    b[NH * 2 + j][1] = *(const v8s*)(bp + c1);
  }
}

// ---------------------------------------------------------------------------
// gemm256: C[M,N] = A[M,K] @ BT[N,K]^T, bf16 in / (bf16|f32) out.
//   GATHER: 0 = A rows linear; 1 = proj gather (token rows, par = stream).
//   OSCAT : 0 = f32 linear out (+par*M*N); 1/2 = bf16 out scattered to
//           interleaved token rows (even/odd).
// 8-phase counted-vmcnt schedule; see round-1 notes.
// Requires: M%256==0, N%256==0, K%128==0, grid.x%8==0.
// ---------------------------------------------------------------------------
template <int GATHER, int OSCAT>
__global__ __launch_bounds__(512, 2) void gemm256(
    const unsigned short* __restrict__ A,
    const unsigned short* __restrict__ BT0,
    const unsigned short* __restrict__ BT1,
    void* __restrict__ Cout, int M, int N, int K, int NBN) {
  __shared__ __align__(16) unsigned short lds[65536];   // 128 KiB
  const int tid = threadIdx.x;
  const int par = blockIdx.y;
  const unsigned short* __restrict__ BT = par ? BT1 : BT0;

  int wg = blockIdx.x;
  const int cpx = gridDim.x >> 3;            // bijective XCD swizzle (x%8==0)
  wg = (wg & 7) * cpx + (wg >> 3);
  const int m0 = (wg / NBN) * 256, n0 = (wg % NBN) * 256;

  const int w = tid >> 6, lane = tid & 63;
  const int wm = w >> 2, wn = w & 3;         // wave tile: rows wm*128, cols wn*64
  const int r = lane & 15, q = lane >> 4;
  const int rs = r & 7;
  const int c0 = ((q ^ rs) << 3);            // swizzled ushort col, ks=0
  const int c1 = (((4 + q) ^ rs) << 3);      // ks=1
  const int brow = (wn & 1) << 6;
  const int AbaseE = (2 + wm) * 8192, BbaseE = (wn >> 1) * 8192;
  const int AbaseO = (6 + wm) * 8192, BbaseO = (4 + (wn >> 1)) * 8192;

  const int sr0 = tid >> 3, sslot = tid & 7; // staging coords
  const int NT = K >> 6, NIT = NT >> 1;

  auto stageB = [&](int p, int tt) {
    unsigned short* dst = &lds[(((tt << 2) + p) & 7) * 8192 + w * 512];
#pragma unroll
    for (int cc = 0; cc < 2; ++cc) {
      const int row = sr0 + cc * 64;
      const int g = ((sslot ^ (row & 7)) << 3);
      GL2LDS(BT + (size_t)(n0 + p * 128 + row) * K + tt * 64 + g, dst + cc * 4096);
    }
  };
  auto stageA = [&](int p, int tt) {
    unsigned short* dst = &lds[(((tt << 2) + 2 + p) & 7) * 8192 + w * 512];
#pragma unroll
    for (int cc = 0; cc < 2; ++cc) {
      const int row = sr0 + cc * 64;
      const int g = ((sslot ^ (row & 7)) << 3);
      int ar = m0 + p * 128 + row;
      if constexpr (GATHER) ar = ((ar >> 10) << 11) + ((ar & 1023) << 1) + par;
      GL2LDS(A + (size_t)ar * K + tt * 64 + g, dst + cc * 4096);
    }
  };

  v4f acc[8][4] = {};
  v8s a[4][2], b[4][2];

  // prologue: h0..h5 = B0(0) B1(0) A0(0) A1(0) B0(1) B1(1)
  stageB(0, 0); stageB(1, 0); stageA(0, 0); stageA(1, 0);
  asm volatile("" ::: "memory");             // pin issue order at vmcnt cut
  stageB(0, 1); stageB(1, 1);
  asm volatile("s_waitcnt vmcnt(4)" ::: "memory");   // tile 0 resident
  S_BARRIER();

  for (int it = 0; it < NIT; ++it) {
    const int t = it << 1;
    const bool more = (it + 1 < NIT);

    // ---- phase 1: A-lo + B-lo reads (12x b128), stage A0(t+1) -> region 6
    read_a_half(lds, AbaseE, 0, r, c0, c1, a);
    read_b_half<0>(lds, BbaseE, brow, r, c0, c1, b);
    stageA(0, t + 1);
    S_BARRIER();
    mfma_quad<0, 0>(acc, a, b);
    S_BARRIER();
    // ---- phase 2: B-hi reads, stage A1(t+1) -> region 7
    read_b_half<1>(lds, BbaseE, brow, r, c0, c1, b);
    stageA(1, t + 1);
    S_BARRIER();
    mfma_quad<0, 1>(acc, a, b);
    S_BARRIER();
    // ---- phase 3: A-hi reads, stage B0(t+2) -> region 0 (B(t) reads done ph2)
    read_a_half(lds, AbaseE, 1, r, c0, c1, a);
    if (more) stageB(0, t + 2);
    S_BARRIER();
    mfma_quad<1, 0>(acc, a, b);
    S_BARRIER();
    // ---- phase 4: stage B1(t+2) -> region 1; checkpoint tile t+1
    if (more) stageB(1, t + 2);
    S_BARRIER();
    mfma_quad<1, 1>(acc, a, b);
    if (more) { asm volatile("s_waitcnt vmcnt(4)" ::: "memory"); }
    else      { asm volatile("s_waitcnt vmcnt(0)" ::: "memory"); }
    S_BARRIER();

    // ---- phase 5 (tile t+1): stage A0(t+2) -> region 2 (A(t) reads done ph3)
    read_a_half(lds, AbaseO, 0, r, c0, c1, a);
    read_b_half<0>(lds, BbaseO, brow, r, c0, c1, b);
    if (more) stageA(0, t + 2);
    S_BARRIER();
    mfma_quad<0, 0>(acc, a, b);
    S_BARRIER();
    // ---- phase 6: stage A1(t+2) -> region 3
    read_b_half<1>(lds, BbaseO, brow, r, c0, c1, b);
    if (more) stageA(1, t + 2);
    S_BARRIER();
    mfma_quad<0, 1>(acc, a, b);
    S_BARRIER();
    // ---- phase 7: stage B0(t+3) -> region 4 (B(t+1) reads done ph6)
    read_a_half(lds, AbaseO, 1, r, c0, c1, a);
    if (more) stageB(0, t + 3);
    S_BARRIER();
    mfma_quad<1, 0>(acc, a, b);
    S_BARRIER();
    // ---- phase 8: stage B1(t+3) -> region 5; checkpoint tile t+2
    if (more) stageB(1, t + 3);
    S_BARRIER();
    mfma_quad<1, 1>(acc, a, b);
    if (more) { asm volatile("s_waitcnt vmcnt(4)" ::: "memory"); }
    S_BARRIER();
  }

  // ---- epilogue
  float* Cf = (float*)Cout + (size_t)par * M * N;
  unsigned short* Cb = (unsigned short*)Cout;
#pragma unroll
  for (int tm = 0; tm < 8; ++tm) {
    const int rowm = m0 + wm * 128 + tm * 16 + q * 4;
#pragma unroll
    for (int tn = 0; tn < 4; ++tn) {
      const int col = n0 + wn * 64 + tn * 16 + r;
#pragma unroll
      for (int p = 0; p < 4; ++p) {
        if constexpr (OSCAT == 0) {
          Cf[(size_t)(rowm + p) * N + col] = acc[tm][tn][p];
        } else {
          const int ar = rowm + p;
          const int orow = ((ar >> 10) << 11) + ((ar & 1023) << 1) + (OSCAT - 1);
          Cb[(size_t)orow * N + col] = f2bf(acc[tm][tn][p]);
        }
      }
    }
  }
}

// ---------------------------------------------------------------------------
// QKVall -> Q,K (B,NH,T,HS) with RoPE. One block per token.
// ---------------------------------------------------------------------------
__global__ __launch_bounds__(256) void scatter_rope(
    const unsigned short* __restrict__ qkv,
    const float* __restrict__ cosb, const float* __restrict__ sinb,
    unsigned short* __restrict__ Q, unsigned short* __restrict__ K) {
  const int token = blockIdx.x;          // b*2048 + t
  const int b = token >> 11, t = token & 2047;
  const unsigned short* src = qkv + (size_t)token * 6144;
  for (int i = threadIdx.x; i < 2048; i += 256) {
    const int d = i & 127, h = i >> 7;
    const float cv = cosb[t * 128 + d];
    const float sv = sinb[t * 128 + d];
    const int   mate = (d < 64) ? i + 64 : i - 64;
    const float sgn  = (d < 64) ? -1.f : 1.f;
    const float qv = b2f(src[i]),        qm = b2f(src[mate]) * sgn;
    const float kv = b2f(src[2048 + i]), km = b2f(src[2048 + mate]) * sgn;
    const size_t off = ((size_t)(b * 16 + h) * 2048 + t) * 128 + d;
    Q[off] = f2bf(qv * cv + qm * sv);
    K[off] = f2bf(kv * cv + km * sv);
  }
}

// ---------------------------------------------------------------------------
// V part of QKVall -> Vt (B*NH, HS, T) via LDS-tiled transpose.
// ---------------------------------------------------------------------------
__global__ __launch_bounds__(256) void transpose_v(
    const unsigned short* __restrict__ qkv, unsigned short* __restrict__ Vt) {
  __shared__ unsigned short tile[128][129];
  const int bh = blockIdx.x >> 4, tt = blockIdx.x & 15;
  const int b = bh >> 4, h = bh & 15;
  const int tid = threadIdx.x;
  const int d0 = tid & 127, t0 = tid >> 7;
#pragma unroll 4
  for (int i = 0; i < 64; ++i) {
    int tl = i * 2 + t0;
    tile[tl][d0] =
        qkv[((size_t)(b * 2048 + tt * 128 + tl)) * 6144 + 4096 + h * 128 + d0];
  }
  __syncthreads();
#pragma unroll 4
  for (int i = 0; i < 64; ++i) {
    int dd = i * 2 + t0;
    Vt[((size_t)(bh * 128 + dd)) * 2048 + tt * 128 + d0] = tile[d0][dd];
  }
}

// ---------------------------------------------------------------------------
// Flash attention. BQ=128, BK=64, 4 waves; each wave owns 32 q-rows (two
// 16-row groups rg=0,1) so every K/V fragment read from LDS feeds 2x MFMAs.
// Block pr handles q-tiles (15-pr) then (pr): 2*(16-pr) + 2*(pr+1) = 34
// BK-tiles for every block. Grid 256 = 1 block/CU (LDS 82 KB). K/V double-
// buffered, prefetch + s_waitcnt vmcnt(8) (counted; 0 only on last tile),
// raw s_barrier only. Q fragments direct from global. Defer-max softmax
// (T13): skip alpha-rescale when max grows < 60 raw (P <= 2^7.7, f32 acc).
// Block mapping keeps all 8 pr of a bh on one XCD guess -> K/V L2-resident.
// ---------------------------------------------------------------------------
#define SIG 0.1275174038536989f   // (1/sqrt(128)) * log2(e)

__global__ __launch_bounds__(256, 1) void attn_flash(
    const unsigned short* __restrict__ Q, const unsigned short* __restrict__ K,
    const unsigned short* __restrict__ Vt, unsigned short* __restrict__ Y) {
  __shared__ __align__(16) unsigned short Ks[2][64 * 128];   // 32 KB
  __shared__ __align__(16) unsigned short Vs[2][128 * 64];   // 32 KB
  __shared__ __align__(16) unsigned short Pl[4][32 * 72];    // 18 KB

  const int x = blockIdx.x;
  const int bh = (x & 7) * 4 + ((x >> 3) & 3);   // same-bh blocks share an XCD
  const int pr = x >> 5;                          // 0..7
  const int tid = threadIdx.x, w = tid >> 6, lane = tid & 63;
  const int r = lane & 15, q = lane >> 4;
  const int b = bh >> 4, h = bh & 15;
  const size_t kbase = (size_t)bh * 2048 * 128;
  const size_t vbase = (size_t)bh * 128 * 2048;
  const int vrow = lane >> 3, pc = lane & 7;
  unsigned short* Pw = &Pl[w][0];

  for (int ph = 0; ph < 2; ++ph) {
    const int qt = ph ? pr : (15 - pr);

    // ---- Q fragments straight from global (16B/lane, no LDS round-trip)
    const size_t qbase = ((size_t)bh * 2048 + qt * 128) * 128;
    v8s qf[2][4];
#pragma unroll
    for (int rg = 0; rg < 2; ++rg)
#pragma unroll
      for (int ki = 0; ki < 4; ++ki)
        qf[rg][ki] = *(const v8s*)&Q[qbase +
                                     (size_t)(w * 32 + rg * 16 + r) * 128 +
                                     (ki * 4 + q) * 8];

    float mrun[2][4], lrun[2][4];
    v4f O[2][8] = {};
#pragma unroll
    for (int rg = 0; rg < 2; ++rg)
#pragma unroll
      for (int p = 0; p < 4; ++p) { mrun[rg][p] = -3.0e38f; lrun[rg][p] = 0.f; }

    const int nkt = 2 * qt + 2;

    auto stageKV = [&](int kt, int buf) {
#pragma unroll
      for (int i = 0; i < 4; ++i) {
        const int key = w * 16 + i * 4 + q;
        const int gs = r ^ (key & 15);
        GL2LDS(K + kbase + ((size_t)kt * 64 + key) * 128 + gs * 8,
               &Ks[buf][(w * 16 + i * 4) * 128]);
      }
#pragma unroll
      for (int i = 0; i < 4; ++i) {
        const int d = w * 32 + i * 8 + vrow;
        const int gs = pc ^ (d & 7);
        GL2LDS(Vt + vbase + (size_t)d * 2048 + kt * 64 + gs * 8,
               &Vs[buf][(w * 32 + i * 8) * 64]);
      }
    };

    stageKV(0, 0);
    for (int kt = 0; kt < nkt; ++kt) {
      const int buf = kt & 1;
      if (kt + 1 < nkt) {
        stageKV(kt + 1, buf ^ 1);                        // prefetch next tile
        asm volatile("s_waitcnt vmcnt(8)" ::: "memory"); // tile kt resident
      } else {
        asm volatile("s_waitcnt vmcnt(0)" ::: "memory"); // no prefetch: drain
      }
      S_BARRIER();

      // ---- S = Q K^T  (rows: w*32 + rg*16 + q*4+p, cols: tn*16+r)
      v4f S[2][4] = {};
      __builtin_amdgcn_s_setprio(1);
#pragma unroll
      for (int ki = 0; ki < 4; ++ki) {
        v8s kf[4];
#pragma unroll
        for (int tn = 0; tn < 4; ++tn) {
          const int key = tn * 16 + r;
          const int c = (ki * 4 + q) ^ r;
          kf[tn] = *(const v8s*)&Ks[buf][key * 128 + c * 8];
        }
#pragma unroll
        for (int tn = 0; tn < 4; ++tn) {
          S[0][tn] = __builtin_amdgcn_mfma_f32_16x16x32_bf16(
              qf[0][ki], kf[tn], S[0][tn], 0, 0, 0);
          S[1][tn] = __builtin_amdgcn_mfma_f32_16x16x32_bf16(
              qf[1][ki], kf[tn], S[1][tn], 0, 0, 0);
        }
      }
      __builtin_amdgcn_s_setprio(0);

      // ---- causal mask (last two k-tiles only)
      if (kt >= nkt - 2) {
        const int off = (kt - (nkt - 2)) * 64;
#pragma unroll
        for (int rg = 0; rg < 2; ++rg)
#pragma unroll
          for (int tn = 0; tn < 4; ++tn)
#pragma unroll
            for (int p = 0; p < 4; ++p) {
              const int tq = w * 32 + rg * 16 + q * 4 + p;  // local q-row
              const int kg = tn * 16 + r + off;             // local key
              if (kg > tq) S[rg][tn][p] = -3.0e38f;
            }
      }

      // ---- online softmax (base-2) with defer-max vote
      float mx[2][4];
#pragma unroll
      for (int rg = 0; rg < 2; ++rg)
#pragma unroll
        for (int p = 0; p < 4; ++p) {
          float m0v = fmaxf(fmaxf(S[rg][0][p], S[rg][1][p]),
                            fmaxf(S[rg][2][p], S[rg][3][p]));
#pragma unroll
          for (int o = 1; o < 16; o <<= 1) m0v = fmaxf(m0v, __shfl_xor(m0v, o, 64));
          mx[rg][p] = m0v;
        }
      int need = 0;
#pragma unroll
      for (int rg = 0; rg < 2; ++rg)
#pragma unroll
        for (int p = 0; p < 4; ++p)
          need |= (mx[rg][p] > mrun[rg][p] + 60.0f) ? 1 : 0;

      if (__any(need)) {
        // rescale path
#pragma unroll
        for (int rg = 0; rg < 2; ++rg)
#pragma unroll
          for (int p = 0; p < 4; ++p) {
            const float mnew = fmaxf(mrun[rg][p], mx[rg][p]);
            const float alpha = exp2f((mrun[rg][p] - mnew) * SIG);
            mrun[rg][p] = mnew;
            float sum = 0.f;
#pragma unroll
            for (int tn = 0; tn < 4; ++tn) {
              const float pv = exp2f((S[rg][tn][p] - mnew) * SIG);
              S[rg][tn][p] = pv;
              sum += pv;
            }
#pragma unroll
            for (int o = 1; o < 16; o <<= 1) sum += __shfl_xor(sum, o, 64);
            lrun[rg][p] = lrun[rg][p] * alpha + sum;
#pragma unroll
            for (int tn = 0; tn < 8; ++tn) O[rg][tn][p] *= alpha;
          }
      } else {
        // deferred path: keep old max, no O rescale (P bounded by 2^(60*SIG))
#pragma unroll
        for (int rg = 0; rg < 2; ++rg)
#pragma unroll
          for (int p = 0; p < 4; ++p) {
            float sum = 0.f;
#pragma unroll
            for (int tn = 0; tn < 4; ++tn) {
              const float pv = exp2f((S[rg][tn][p] - mrun[rg][p]) * SIG);
              S[rg][tn][p] = pv;
              sum += pv;
            }
#pragma unroll
            for (int o = 1; o < 16; o <<= 1) sum += __shfl_xor(sum, o, 64);
            lrun[rg][p] += sum;
          }
      }

      // ---- P (bf16) to LDS, stride 72; wave-local region
#pragma unroll
      for (int rg = 0; rg < 2; ++rg)
#pragma unroll
        for (int tn = 0; tn < 4; ++tn)
#pragma unroll
          for (int p = 0; p < 4; ++p)
            Pw[(rg * 16 + q * 4 + p) * 72 + tn * 16 + r] = f2bf(S[rg][tn][p]);

      // ---- O += P V   (A=P rows, B=Vt rows; vf shared across row-groups)
      __builtin_amdgcn_s_setprio(1);
#pragma unroll
      for (int ki = 0; ki < 2; ++ki) {
        v8s vf[8];
#pragma unroll
        for (int tn = 0; tn < 8; ++tn) {
          const int d = tn * 16 + r;
          const int c = (ki * 4 + q) ^ (d & 7);
          vf[tn] = *(const v8s*)&Vs[buf][d * 64 + c * 8];
        }
        const v8s pf0 = *(const v8s*)&Pw[r * 72 + (ki * 4 + q) * 8];
        const v8s pf1 = *(const v8s*)&Pw[(16 + r) * 72 + (ki * 4 + q) * 8];
#pragma unroll
        for (int tn = 0; tn < 8; ++tn) {
          O[0][tn] = __builtin_amdgcn_mfma_f32_16x16x32_bf16(
              pf0, vf[tn], O[0][tn], 0, 0, 0);
          O[1][tn] = __builtin_amdgcn_mfma_f32_16x16x32_bf16(
              pf1, vf[tn], O[1][tn], 0, 0, 0);
        }
      }
      __builtin_amdgcn_s_setprio(0);

      // all LDS reads of buf retired before restage of buf next+1 iter
      asm volatile("s_waitcnt lgkmcnt(0)" ::: "memory");
      S_BARRIER();
    }

    // ---- epilogue: O/l -> Y[(b*T+t)][h*128+d]
#pragma unroll
    for (int rg = 0; rg < 2; ++rg)
#pragma unroll
      for (int p = 0; p < 4; ++p) {
        const float inv = 1.0f / lrun[rg][p];
        const int t = qt * 128 + w * 32 + rg * 16 + q * 4 + p;
#pragma unroll
        for (int tn = 0; tn < 8; ++tn)
          Y[((size_t)(b * 2048 + t)) * 2048 + h * 128 + tn * 16 + r] =
              f2bf(O[rg][tn][p] * inv);
      }
  }
}

// ---------------------------------------------------------------------------
// Launch
// ---------------------------------------------------------------------------
extern "C" void kernel_launch(void* const* d_in, const int* in_sizes, int n_in,
                              void* d_out, int out_size, void* d_ws, size_t ws_size,
                              hipStream_t stream) {
  const float* x_a   = (const float*)d_in[0];
  const float* x_b   = (const float*)d_in[1];
  const float* cosb  = (const float*)d_in[2];
  const float* sinb  = (const float*)d_in[3];
  const float* Wqkv_a  = (const float*)d_in[5];
  const float* Wqkv_b  = (const float*)d_in[6];
  const float* Wproj_a = (const float*)d_in[7];
  const float* Wproj_b = (const float*)d_in[8];
  float* out = (float*)d_out;

  if (ws_size < 100663296u) return;

  char* ws = (char*)d_ws;
  unsigned short* QKVall = (unsigned short*)(ws);                // [0,48M)
  unsigned short* XA     = (unsigned short*)(ws + 50331648);     // [48,56M)
  unsigned short* WQT    = (unsigned short*)(ws + 67108864);     // [64,88M)
  unsigned short* Qb     = (unsigned short*)(ws + 50331648);     // [48,64M)
  unsigned short* Kb     = (unsigned short*)(ws + 67108864);     // [64,80M)
  unsigned short* Vtb    = (unsigned short*)(ws + 83886080);     // [80,96M)
  unsigned short* Yb     = (unsigned short*)(ws);                // [0,16M)
  unsigned short* WPT_A  = (unsigned short*)(ws + 16777216);     // [16,24M)
  unsigned short* WPT_B  = (unsigned short*)(ws + 25165824);     // [24,32M)

  // phase 1: conversions + qkv GEMMs (token-scattered output rows)
  hipLaunchKernelGGL(f32_to_bf16_2, dim3(8192), dim3(256), 0, stream,
                     (const float4*)x_a, (const float4*)x_b, (uint2*)XA, 1048576);
  hipLaunchKernelGGL(transpose_f32_bf16, dim3(96, 32, 1), dim3(256), 0, stream,
                     Wqkv_a, Wqkv_a, WQT, WQT, 2048, 6144);
  hipLaunchKernelGGL((gemm256<0, 1>), dim3(192, 1), dim3(512), 0, stream,
                     XA, WQT, WQT, QKVall, 2048, 6144, 2048, 24);
  hipLaunchKernelGGL(transpose_f32_bf16, dim3(96, 32, 1), dim3(256), 0, stream,
                     Wqkv_b, Wqkv_b, WQT, WQT, 2048, 6144);
  hipLaunchKernelGGL((gemm256<0, 2>), dim3(192, 1), dim3(512), 0, stream,
                     XA + (size_t)4194304, WQT, WQT, QKVall, 2048, 6144, 2048, 24);

  // phase 2: RoPE Q/K + V transpose (both read QKVall)
  hipLaunchKernelGGL(scatter_rope, dim3(4096), dim3(256), 0, stream,
                     QKVall, cosb, sinb, Qb, Kb);
  hipLaunchKernelGGL(transpose_v, dim3(512), dim3(256), 0, stream,
                     QKVall, Vtb);

  // phase 3: both Wproj transposes in one launch (dead QKVall region)
  hipLaunchKernelGGL(transpose_f32_bf16, dim3(32, 32, 2), dim3(256), 0, stream,
                     Wproj_a, Wproj_b, WPT_A, WPT_B, 2048, 2048);

  // phase 4: flash attention -> Yb (BQ=128, balanced q-tile pairs)
  hipLaunchKernelGGL(attn_flash, dim3(256), dim3(256), 0, stream,
                     Qb, Kb, Vtb, Yb);

  // phase 5: both output projections in one launch (y = stream parity)
  hipLaunchKernelGGL((gemm256<1, 0>), dim3(64, 2), dim3(512), 0, stream,
                     Yb, WPT_A, WPT_B, out, 2048, 2048, 2048, 8);
}

// Round 4
// 472.047 us; speedup vs baseline: 1.1375x; 1.1375x over previous
//
#include <hip/hip_runtime.h>
#include <hip/hip_bf16.h>

// ---------------------------------------------------------------------------
// SparseCausalSelfAttention: B=2,T=2048,E=2048,NH=16,HS=128.
// I/O float32; internal bf16 MFMA, fp32 acc. Mask = fixed (t%2==0) interleave.
//
// ws plan (peak 96 MiB):
//   [ 0,48M) QKVall (B*T,6144) -> later Yb [0,16M), WPT_A [16,24M), WPT_B [24,32M)
//   [48,56M) XA ; [56,64M) XB  -> later Qb [48,64M)
//   [64,88M) WQT               -> later Kb [64,80M), Vtb [80,96M)
//
// GEMMs: 256x256 tile, BK=64, 8 waves (2Mx4N), 8-phase counted-vmcnt schedule.
// Attn: round-2 structure (BQ=64, 4 waves, 2 blocks/CU, double-buffered K/V,
// counted vmcnt, XCD-local mapping) + shuffle-free softmax: lane-local
// defer-max vote (exact) and per-lane distributed row-sums reduced once in
// the epilogue. Zero cross-lane ops in the steady-state k-loop.
// ---------------------------------------------------------------------------

typedef __attribute__((ext_vector_type(8))) short v8s;   // 8 bf16 (4 VGPRs)
typedef __attribute__((ext_vector_type(4))) float v4f;   // MFMA accumulator

#define GL2LDS(gptr, lptr)                                              \
  __builtin_amdgcn_global_load_lds(                                     \
      (const __attribute__((address_space(1))) void*)(gptr),            \
      (__attribute__((address_space(3))) void*)(lptr), 16, 0, 0)

#define S_BARRIER() asm volatile("s_barrier" ::: "memory")

__device__ __forceinline__ float b2f(unsigned short u) {
  return __uint_as_float(((unsigned int)u) << 16);
}
__device__ __forceinline__ unsigned short f2bf(float f) {
  unsigned int u = __float_as_uint(f);
  u += 0x7fffu + ((u >> 16) & 1u);   // RNE
  return (unsigned short)(u >> 16);
}

// ---------------------------------------------------------------------------
// Both x streams -> bf16 in one launch (XA,XB contiguous in ws).
// ---------------------------------------------------------------------------
__global__ __launch_bounds__(256) void f32_to_bf16_2(
    const float4* __restrict__ a, const float4* __restrict__ b,
    uint2* __restrict__ out, int n4each) {
  int i = blockIdx.x * 256 + threadIdx.x;
  if (i >= 2 * n4each) return;
  float4 v = (i < n4each) ? a[i] : b[i - n4each];
  uint2 o;
  o.x = (unsigned int)f2bf(v.x) | ((unsigned int)f2bf(v.y) << 16);
  o.y = (unsigned int)f2bf(v.z) | ((unsigned int)f2bf(v.w) << 16);
  out[i] = o;
}

// ---------------------------------------------------------------------------
// Transpose f32 (R x C) -> bf16 (C x R); z selects (in0->out0)/(in1->out1).
// ---------------------------------------------------------------------------
__global__ __launch_bounds__(256) void transpose_f32_bf16(
    const float* __restrict__ in0, const float* __restrict__ in1,
    unsigned short* __restrict__ out0, unsigned short* __restrict__ out1,
    int R, int C) {
  const float* in = blockIdx.z ? in1 : in0;
  unsigned short* out = blockIdx.z ? out1 : out0;
  __shared__ unsigned short tile[64][65];
  const int bc = blockIdx.x * 64, br = blockIdx.y * 64;
  const int c  = threadIdx.x & 63;
  const int r0 = threadIdx.x >> 6;
  for (int r = r0; r < 64; r += 4)
    tile[r][c] = f2bf(in[(size_t)(br + r) * C + bc + c]);
  __syncthreads();
  for (int rr = r0; rr < 64; rr += 4)
    out[(size_t)(bc + rr) * R + br + c] = tile[c][rr];
}

// ---------------------------------------------------------------------------
// 256x256-tile GEMM helpers.
// ---------------------------------------------------------------------------
template <int MH, int NH>
__device__ __forceinline__ void mfma_quad(v4f (&acc)[8][4], const v8s (&a)[4][2],
                                          const v8s (&b)[4][2]) {
  __builtin_amdgcn_s_setprio(1);
#pragma unroll
  for (int ks = 0; ks < 2; ++ks)
#pragma unroll
    for (int i = 0; i < 4; ++i)
#pragma unroll
      for (int j = 0; j < 2; ++j)
        acc[MH * 4 + i][NH * 2 + j] = __builtin_amdgcn_mfma_f32_16x16x32_bf16(
            a[i][ks], b[NH * 2 + j][ks], acc[MH * 4 + i][NH * 2 + j], 0, 0, 0);
  __builtin_amdgcn_s_setprio(0);
}

__device__ __forceinline__ void read_a_half(const unsigned short* lds, int base,
                                            int mh, int r, int c0, int c1,
                                            v8s (&a)[4][2]) {
#pragma unroll
  for (int i = 0; i < 4; ++i) {
    const unsigned short* ap = lds + base + (mh * 64 + i * 16 + r) * 64;
    a[i][0] = *(const v8s*)(ap + c0);
    a[i][1] = *(const v8s*)(ap + c1);
  }
}

template <int NH>
__device__ __forceinline__ void read_b_half(const unsigned short* lds, int base,
                                            int brow, int r, int c0, int c1,
                                            v8s (&b)[4][2]) {
#pragma unroll
  for (int j = 0; j < 2; ++j) {
    const unsigned short* bp = lds + base + (brow + (NH * 2 + j) * 16 + r) * 64;
    b[NH * 2 + j][0] = *(const v8s*)(bp + c0);
    b[NH * 2 + j][1] = *(const v8s*)(bp + c1);
  }
}

// ---------------------------------------------------------------------------
// gemm256: C[M,N] = A[M,K] @ BT[N,K]^T, bf16 in / (bf16|f32) out.
//   GATHER: 0 = A rows linear; 1 = proj gather (token rows, par = stream).
//   OSCAT : 0 = f32 linear out (+par*M*N); 1/2 = bf16 out scattered to
//           interleaved token rows (even/odd).
// 8-phase counted-vmcnt schedule; see round-1 notes.
// Requires: M%256==0, N%256==0, K%128==0, grid.x%8==0.
// ---------------------------------------------------------------------------
template <int GATHER, int OSCAT>
__global__ __launch_bounds__(512, 2) void gemm256(
    const unsigned short* __restrict__ A,
    const unsigned short* __restrict__ BT0,
    const unsigned short* __restrict__ BT1,
    void* __restrict__ Cout, int M, int N, int K, int NBN) {
  __shared__ __align__(16) unsigned short lds[65536];   // 128 KiB
  const int tid = threadIdx.x;
  const int par = blockIdx.y;
  const unsigned short* __restrict__ BT = par ? BT1 : BT0;

  int wg = blockIdx.x;
  const int cpx = gridDim.x >> 3;            // bijective XCD swizzle (x%8==0)
  wg = (wg & 7) * cpx + (wg >> 3);
  const int m0 = (wg / NBN) * 256, n0 = (wg % NBN) * 256;

  const int w = tid >> 6, lane = tid & 63;
  const int wm = w >> 2, wn = w & 3;         // wave tile: rows wm*128, cols wn*64
  const int r = lane & 15, q = lane >> 4;
  const int rs = r & 7;
  const int c0 = ((q ^ rs) << 3);            // swizzled ushort col, ks=0
  const int c1 = (((4 + q) ^ rs) << 3);      // ks=1
  const int brow = (wn & 1) << 6;
  const int AbaseE = (2 + wm) * 8192, BbaseE = (wn >> 1) * 8192;
  const int AbaseO = (6 + wm) * 8192, BbaseO = (4 + (wn >> 1)) * 8192;

  const int sr0 = tid >> 3, sslot = tid & 7; // staging coords
  const int NT = K >> 6, NIT = NT >> 1;

  auto stageB = [&](int p, int tt) {
    unsigned short* dst = &lds[(((tt << 2) + p) & 7) * 8192 + w * 512];
#pragma unroll
    for (int cc = 0; cc < 2; ++cc) {
      const int row = sr0 + cc * 64;
      const int g = ((sslot ^ (row & 7)) << 3);
      GL2LDS(BT + (size_t)(n0 + p * 128 + row) * K + tt * 64 + g, dst + cc * 4096);
    }
  };
  auto stageA = [&](int p, int tt) {
    unsigned short* dst = &lds[(((tt << 2) + 2 + p) & 7) * 8192 + w * 512];
#pragma unroll
    for (int cc = 0; cc < 2; ++cc) {
      const int row = sr0 + cc * 64;
      const int g = ((sslot ^ (row & 7)) << 3);
      int ar = m0 + p * 128 + row;
      if constexpr (GATHER) ar = ((ar >> 10) << 11) + ((ar & 1023) << 1) + par;
      GL2LDS(A + (size_t)ar * K + tt * 64 + g, dst + cc * 4096);
    }
  };

  v4f acc[8][4] = {};
  v8s a[4][2], b[4][2];

  // prologue: h0..h5 = B0(0) B1(0) A0(0) A1(0) B0(1) B1(1)
  stageB(0, 0); stageB(1, 0); stageA(0, 0); stageA(1, 0);
  asm volatile("" ::: "memory");             // pin issue order at vmcnt cut
  stageB(0, 1); stageB(1, 1);
  asm volatile("s_waitcnt vmcnt(4)" ::: "memory");   // tile 0 resident
  S_BARRIER();

  for (int it = 0; it < NIT; ++it) {
    const int t = it << 1;
    const bool more = (it + 1 < NIT);

    // ---- phase 1: A-lo + B-lo reads (12x b128), stage A0(t+1) -> region 6
    read_a_half(lds, AbaseE, 0, r, c0, c1, a);
    read_b_half<0>(lds, BbaseE, brow, r, c0, c1, b);
    stageA(0, t + 1);
    S_BARRIER();
    mfma_quad<0, 0>(acc, a, b);
    S_BARRIER();
    // ---- phase 2: B-hi reads, stage A1(t+1) -> region 7
    read_b_half<1>(lds, BbaseE, brow, r, c0, c1, b);
    stageA(1, t + 1);
    S_BARRIER();
    mfma_quad<0, 1>(acc, a, b);
    S_BARRIER();
    // ---- phase 3: A-hi reads, stage B0(t+2) -> region 0 (B(t) reads done ph2)
    read_a_half(lds, AbaseE, 1, r, c0, c1, a);
    if (more) stageB(0, t + 2);
    S_BARRIER();
    mfma_quad<1, 0>(acc, a, b);
    S_BARRIER();
    // ---- phase 4: stage B1(t+2) -> region 1; checkpoint tile t+1
    if (more) stageB(1, t + 2);
    S_BARRIER();
    mfma_quad<1, 1>(acc, a, b);
    if (more) { asm volatile("s_waitcnt vmcnt(4)" ::: "memory"); }
    else      { asm volatile("s_waitcnt vmcnt(0)" ::: "memory"); }
    S_BARRIER();

    // ---- phase 5 (tile t+1): stage A0(t+2) -> region 2 (A(t) reads done ph3)
    read_a_half(lds, AbaseO, 0, r, c0, c1, a);
    read_b_half<0>(lds, BbaseO, brow, r, c0, c1, b);
    if (more) stageA(0, t + 2);
    S_BARRIER();
    mfma_quad<0, 0>(acc, a, b);
    S_BARRIER();
    // ---- phase 6: stage A1(t+2) -> region 3
    read_b_half<1>(lds, BbaseO, brow, r, c0, c1, b);
    if (more) stageA(1, t + 2);
    S_BARRIER();
    mfma_quad<0, 1>(acc, a, b);
    S_BARRIER();
    // ---- phase 7: stage B0(t+3) -> region 4 (B(t+1) reads done ph6)
    read_a_half(lds, AbaseO, 1, r, c0, c1, a);
    if (more) stageB(0, t + 3);
    S_BARRIER();
    mfma_quad<1, 0>(acc, a, b);
    S_BARRIER();
    // ---- phase 8: stage B1(t+3) -> region 5; checkpoint tile t+2
    if (more) stageB(1, t + 3);
    S_BARRIER();
    mfma_quad<1, 1>(acc, a, b);
    if (more) { asm volatile("s_waitcnt vmcnt(4)" ::: "memory"); }
    S_BARRIER();
  }

  // ---- epilogue
  float* Cf = (float*)Cout + (size_t)par * M * N;
  unsigned short* Cb = (unsigned short*)Cout;
#pragma unroll
  for (int tm = 0; tm < 8; ++tm) {
    const int rowm = m0 + wm * 128 + tm * 16 + q * 4;
#pragma unroll
    for (int tn = 0; tn < 4; ++tn) {
      const int col = n0 + wn * 64 + tn * 16 + r;
#pragma unroll
      for (int p = 0; p < 4; ++p) {
        if constexpr (OSCAT == 0) {
          Cf[(size_t)(rowm + p) * N + col] = acc[tm][tn][p];
        } else {
          const int ar = rowm + p;
          const int orow = ((ar >> 10) << 11) + ((ar & 1023) << 1) + (OSCAT - 1);
          Cb[(size_t)orow * N + col] = f2bf(acc[tm][tn][p]);
        }
      }
    }
  }
}

// ---------------------------------------------------------------------------
// QKVall -> Q,K (B,NH,T,HS) with RoPE. One block per token.
// ---------------------------------------------------------------------------
__global__ __launch_bounds__(256) void scatter_rope(
    const unsigned short* __restrict__ qkv,
    const float* __restrict__ cosb, const float* __restrict__ sinb,
    unsigned short* __restrict__ Q, unsigned short* __restrict__ K) {
  const int token = blockIdx.x;          // b*2048 + t
  const int b = token >> 11, t = token & 2047;
  const unsigned short* src = qkv + (size_t)token * 6144;
  for (int i = threadIdx.x; i < 2048; i += 256) {
    const int d = i & 127, h = i >> 7;
    const float cv = cosb[t * 128 + d];
    const float sv = sinb[t * 128 + d];
    const int   mate = (d < 64) ? i + 64 : i - 64;
    const float sgn  = (d < 64) ? -1.f : 1.f;
    const float qv = b2f(src[i]),        qm = b2f(src[mate]) * sgn;
    const float kv = b2f(src[2048 + i]), km = b2f(src[2048 + mate]) * sgn;
    const size_t off = ((size_t)(b * 16 + h) * 2048 + t) * 128 + d;
    Q[off] = f2bf(qv * cv + qm * sv);
    K[off] = f2bf(kv * cv + km * sv);
  }
}

// ---------------------------------------------------------------------------
// V part of QKVall -> Vt (B*NH, HS, T) via LDS-tiled transpose.
// ---------------------------------------------------------------------------
__global__ __launch_bounds__(256) void transpose_v(
    const unsigned short* __restrict__ qkv, unsigned short* __restrict__ Vt) {
  __shared__ unsigned short tile[128][129];
  const int bh = blockIdx.x >> 4, tt = blockIdx.x & 15;
  const int b = bh >> 4, h = bh & 15;
  const int tid = threadIdx.x;
  const int d0 = tid & 127, t0 = tid >> 7;
#pragma unroll 4
  for (int i = 0; i < 64; ++i) {
    int tl = i * 2 + t0;
    tile[tl][d0] =
        qkv[((size_t)(b * 2048 + tt * 128 + tl)) * 6144 + 4096 + h * 128 + d0];
  }
  __syncthreads();
#pragma unroll 4
  for (int i = 0; i < 64; ++i) {
    int dd = i * 2 + t0;
    Vt[((size_t)(bh * 128 + dd)) * 2048 + tt * 128 + d0] = tile[d0][dd];
  }
}

// ---------------------------------------------------------------------------
// Flash attention, BQ=64, BK=64, 4 waves, balanced q-tile pairing:
// block handles q-tiles (31-pr) then (pr) -> 33 k-tiles per block.
// K/V double-buffered in LDS, prefetch + counted s_waitcnt vmcnt(8), raw
// s_barrier only. Q fragments direct from global. XCD-local (b,h) mapping
// keeps K/V L2-resident. LDS 73 KB -> 2 blocks/CU.
// Softmax: shuffle-free steady state. Defer-max vote is LANE-LOCAL (exact:
// mrun uniform per 16-lane row group, so any-lane-partial-exceeds == row
// exceeds). Row sums kept as PER-LANE partials through the k-loop (alpha is
// lane-uniform), reduced once in the epilogue. Rescale path (rare: first
// tile, then ~never since threshold 60 raw = 7.65 exp2-units) does the full
// row-max reduce + O rescale.
// ---------------------------------------------------------------------------
#define SIG 0.1275174038536989f   // (1/sqrt(128)) * log2(e)

__global__ __launch_bounds__(256, 2) void attn_flash(
    const unsigned short* __restrict__ Q, const unsigned short* __restrict__ K,
    const unsigned short* __restrict__ Vt, unsigned short* __restrict__ Y) {
  __shared__ __align__(16) unsigned short Ks[2][64 * 128];
  __shared__ __align__(16) unsigned short Vs[2][128 * 64];
  __shared__ __align__(16) unsigned short Pl[64 * 72];   // P tile, stride 72

  const int x = blockIdx.x;
  const int bh = (x & 7) * 4 + ((x >> 3) & 3);   // same-bh blocks share an XCD
  const int pr = x >> 5;
  const int tid = threadIdx.x, w = tid >> 6, lane = tid & 63;
  const int r = lane & 15, q = lane >> 4;
  const int b = bh >> 4, h = bh & 15;
  const size_t kbase = (size_t)bh * 2048 * 128;
  const size_t vbase = (size_t)bh * 128 * 2048;
  const int vrow = lane >> 3, pc = lane & 7;

  for (int ph = 0; ph < 2; ++ph) {
    const int qt = ph ? pr : (31 - pr);

    // ---- Q fragments straight from global (16B/lane, no LDS round-trip)
    const size_t qbase = ((size_t)bh * 2048 + qt * 64) * 128;
    v8s qf[4];
#pragma unroll
    for (int ki = 0; ki < 4; ++ki)
      qf[ki] = *(const v8s*)&Q[qbase + (size_t)(w * 16 + r) * 128 +
                               (ki * 4 + q) * 8];

    float mrun[4], lrun[4];                 // lrun = PER-LANE partial sums
    v4f O[8] = {};
#pragma unroll
    for (int p = 0; p < 4; ++p) { mrun[p] = -3.0e38f; lrun[p] = 0.f; }

    const int nkt = qt + 1;

    auto stageKV = [&](int kt, int buf) {
#pragma unroll
      for (int i = 0; i < 4; ++i) {
        const int key = w * 16 + i * 4 + q;
        const int gs = r ^ (key & 15);
        GL2LDS(K + kbase + ((size_t)kt * 64 + key) * 128 + gs * 8,
               &Ks[buf][(w * 16 + i * 4) * 128]);
      }
#pragma unroll
      for (int i = 0; i < 4; ++i) {
        const int d = w * 32 + i * 8 + vrow;
        const int gs = pc ^ (d & 7);
        GL2LDS(Vt + vbase + (size_t)d * 2048 + kt * 64 + gs * 8,
               &Vs[buf][(w * 32 + i * 8) * 64]);
      }
    };

    stageKV(0, 0);
    for (int kt = 0; kt < nkt; ++kt) {
      const int buf = kt & 1;
      if (kt + 1 < nkt) {
        stageKV(kt + 1, buf ^ 1);                        // prefetch next tile
        asm volatile("s_waitcnt vmcnt(8)" ::: "memory"); // tile kt resident
      } else {
        asm volatile("s_waitcnt vmcnt(0)" ::: "memory"); // no prefetch: drain
      }
      S_BARRIER();

      // ---- S = Q K^T  (rows: w*16 + q*4+p, cols: tn*16+r)
      v4f S[4] = {};
      __builtin_amdgcn_s_setprio(1);
#pragma unroll
      for (int ki = 0; ki < 4; ++ki) {
        v8s kf[4];
#pragma unroll
        for (int tn = 0; tn < 4; ++tn) {
          const int key = tn * 16 + r;
          const int c = (ki * 4 + q) ^ r;
          kf[tn] = *(const v8s*)&Ks[buf][key * 128 + c * 8];
        }
#pragma unroll
        for (int tn = 0; tn < 4; ++tn)
          S[tn] = __builtin_amdgcn_mfma_f32_16x16x32_bf16(
              qf[ki], kf[tn], S[tn], 0, 0, 0);
      }
      __builtin_amdgcn_s_setprio(0);

      // ---- causal mask (diagonal tile only: kt == qt)
      if (kt == qt) {
#pragma unroll
        for (int tn = 0; tn < 4; ++tn)
#pragma unroll
          for (int p = 0; p < 4; ++p) {
            const int tq = w * 16 + q * 4 + p;        // local q-row
            const int kg = tn * 16 + r;               // local key
            if (kg > tq) S[tn][p] = -3.0e38f;
          }
      }

      // ---- shuffle-free softmax: lane-local vote, per-lane partial sums
      float mxp[4];
      int need = 0;
#pragma unroll
      for (int p = 0; p < 4; ++p) {
        mxp[p] = fmaxf(fmaxf(S[0][p], S[1][p]), fmaxf(S[2][p], S[3][p]));
        need |= (mxp[p] > mrun[p] + 60.0f) ? 1 : 0;
      }

      if (__builtin_expect(__any(need), 0)) {
        // ---- rescale path (rare): full row-max reduce, rescale O and lrun
#pragma unroll
        for (int p = 0; p < 4; ++p) {
          float mx = mxp[p];
#pragma unroll
          for (int o = 1; o < 16; o <<= 1) mx = fmaxf(mx, __shfl_xor(mx, o, 64));
          const float mnew = fmaxf(mrun[p], mx);
          const float alpha = exp2f((mrun[p] - mnew) * SIG);
          mrun[p] = mnew;
          float psum = 0.f;
#pragma unroll
          for (int tn = 0; tn < 4; ++tn) {
            const float pv = exp2f((S[tn][p] - mnew) * SIG);
            S[tn][p] = pv;
            psum += pv;
          }
          lrun[p] = lrun[p] * alpha + psum;   // per-lane partial stays partial
#pragma unroll
          for (int tn = 0; tn < 8; ++tn) O[tn][p] *= alpha;
        }
      } else {
        // ---- deferred path: old max, no O rescale, no cross-lane ops
#pragma unroll
        for (int p = 0; p < 4; ++p) {
          float psum = 0.f;
#pragma unroll
          for (int tn = 0; tn < 4; ++tn) {
            const float pv = exp2f((S[tn][p] - mrun[p]) * SIG);
            S[tn][p] = pv;
            psum += pv;
          }
          lrun[p] += psum;
        }
      }

      // ---- P (bf16) to LDS, stride 72; wave-local rows only
#pragma unroll
      for (int tn = 0; tn < 4; ++tn)
#pragma unroll
        for (int p = 0; p < 4; ++p) {
          const int m = w * 16 + q * 4 + p;
          Pl[m * 72 + tn * 16 + r] = f2bf(S[tn][p]);
        }

      // ---- O += P V   (A=P rows, B=Vt rows)
      __builtin_amdgcn_s_setprio(1);
#pragma unroll
      for (int ki = 0; ki < 2; ++ki) {
        v8s pf, vf[8];
        const int m = w * 16 + r;
        pf = *(const v8s*)&Pl[m * 72 + (ki * 4 + q) * 8];
#pragma unroll
        for (int tn = 0; tn < 8; ++tn) {
          const int d = tn * 16 + r;
          const int c = (ki * 4 + q) ^ (d & 7);
          vf[tn] = *(const v8s*)&Vs[buf][d * 64 + c * 8];
        }
#pragma unroll
        for (int tn = 0; tn < 8; ++tn)
          O[tn] = __builtin_amdgcn_mfma_f32_16x16x32_bf16(
              pf, vf[tn], O[tn], 0, 0, 0);
      }
      __builtin_amdgcn_s_setprio(0);

      // all LDS reads of buf retired before restaging it next iteration
      asm volatile("s_waitcnt lgkmcnt(0)" ::: "memory");
      S_BARRIER();
    }

    // ---- epilogue: reduce per-lane lrun partials across the 16-lane row
    // group (once per q-tile), then O/l -> Y[(b*T+t)][h*128+d]
#pragma unroll
    for (int p = 0; p < 4; ++p) {
      float s = lrun[p];
#pragma unroll
      for (int o = 1; o < 16; o <<= 1) s += __shfl_xor(s, o, 64);
      const float inv = 1.0f / s;
      const int t = qt * 64 + w * 16 + q * 4 + p;
#pragma unroll
      for (int tn = 0; tn < 8; ++tn)
        Y[((size_t)(b * 2048 + t)) * 2048 + h * 128 + tn * 16 + r] =
            f2bf(O[tn][p] * inv);
    }
  }
}

// ---------------------------------------------------------------------------
// Launch
// ---------------------------------------------------------------------------
extern "C" void kernel_launch(void* const* d_in, const int* in_sizes, int n_in,
                              void* d_out, int out_size, void* d_ws, size_t ws_size,
                              hipStream_t stream) {
  const float* x_a   = (const float*)d_in[0];
  const float* x_b   = (const float*)d_in[1];
  const float* cosb  = (const float*)d_in[2];
  const float* sinb  = (const float*)d_in[3];
  const float* Wqkv_a  = (const float*)d_in[5];
  const float* Wqkv_b  = (const float*)d_in[6];
  const float* Wproj_a = (const float*)d_in[7];
  const float* Wproj_b = (const float*)d_in[8];
  float* out = (float*)d_out;

  if (ws_size < 100663296u) return;

  char* ws = (char*)d_ws;
  unsigned short* QKVall = (unsigned short*)(ws);                // [0,48M)
  unsigned short* XA     = (unsigned short*)(ws + 50331648);     // [48,56M)
  unsigned short* WQT    = (unsigned short*)(ws + 67108864);     // [64,88M)
  unsigned short* Qb     = (unsigned short*)(ws + 50331648);     // [48,64M)
  unsigned short* Kb     = (unsigned short*)(ws + 67108864);     // [64,80M)
  unsigned short* Vtb    = (unsigned short*)(ws + 83886080);     // [80,96M)
  unsigned short* Yb     = (unsigned short*)(ws);                // [0,16M)
  unsigned short* WPT_A  = (unsigned short*)(ws + 16777216);     // [16,24M)
  unsigned short* WPT_B  = (unsigned short*)(ws + 25165824);     // [24,32M)

  // phase 1: conversions + qkv GEMMs (token-scattered output rows)
  hipLaunchKernelGGL(f32_to_bf16_2, dim3(8192), dim3(256), 0, stream,
                     (const float4*)x_a, (const float4*)x_b, (uint2*)XA, 1048576);
  hipLaunchKernelGGL(transpose_f32_bf16, dim3(96, 32, 1), dim3(256), 0, stream,
                     Wqkv_a, Wqkv_a, WQT, WQT, 2048, 6144);
  hipLaunchKernelGGL((gemm256<0, 1>), dim3(192, 1), dim3(512), 0, stream,
                     XA, WQT, WQT, QKVall, 2048, 6144, 2048, 24);
  hipLaunchKernelGGL(transpose_f32_bf16, dim3(96, 32, 1), dim3(256), 0, stream,
                     Wqkv_b, Wqkv_b, WQT, WQT, 2048, 6144);
  hipLaunchKernelGGL((gemm256<0, 2>), dim3(192, 1), dim3(512), 0, stream,
                     XA + (size_t)4194304, WQT, WQT, QKVall, 2048, 6144, 2048, 24);

  // phase 2: RoPE Q/K + V transpose (both read QKVall)
  hipLaunchKernelGGL(scatter_rope, dim3(4096), dim3(256), 0, stream,
                     QKVall, cosb, sinb, Qb, Kb);
  hipLaunchKernelGGL(transpose_v, dim3(512), dim3(256), 0, stream,
                     QKVall, Vtb);

  // phase 3: both Wproj transposes in one launch (dead QKVall region)
  hipLaunchKernelGGL(transpose_f32_bf16, dim3(32, 32, 2), dim3(256), 0, stream,
                     Wproj_a, Wproj_b, WPT_A, WPT_B, 2048, 2048);

  // phase 4: flash attention -> Yb (balanced q-tile pairs)
  hipLaunchKernelGGL(attn_flash, dim3(512), dim3(256), 0, stream,
                     Qb, Kb, Vtb, Yb);

  // phase 5: both output projections in one launch (y = stream parity)
  hipLaunchKernelGGL((gemm256<1, 0>), dim3(64, 2), dim3(512), 0, stream,
                     Yb, WPT_A, WPT_B, out, 2048, 2048, 2048, 8);
}

// Round 6
// 445.228 us; speedup vs baseline: 1.2060x; 1.0602x over previous
//
#include <hip/hip_runtime.h>
#include <hip/hip_bf16.h>

// ---------------------------------------------------------------------------
// SparseCausalSelfAttention: B=2,T=2048,E=2048,NH=16,HS=128.
// I/O float32; internal bf16 MFMA, fp32 acc. Mask = fixed (t%2==0) interleave.
//
// ws plan (peak 96 MiB):
//   [ 0,48M) QKVall (B*T,6144) -> later Yb [0,16M), WPT_A [16,24M), WPT_B [24,32M)
//   [48,56M) XA ; [56,64M) XB  -> later Qb [48,64M)
//   [64,88M) WQT               -> later Kb [64,80M), Vtb [80,96M)
//
// 7 launches: prep_a (f2bf + WqkvA^T) -> gemm_a -> WqkvB^T -> gemm_b ->
// rope_tv (RoPE + V^T) -> attn_wpt (flash attn + Wproj^T x2) -> gemm_proj2.
// ---------------------------------------------------------------------------

typedef __attribute__((ext_vector_type(8))) short v8s;   // 8 bf16 (4 VGPRs)
typedef __attribute__((ext_vector_type(4))) float v4f;   // MFMA accumulator

#define GL2LDS(gptr, lptr)                                              \
  __builtin_amdgcn_global_load_lds(                                     \
      (const __attribute__((address_space(1))) void*)(gptr),            \
      (__attribute__((address_space(3))) void*)(lptr), 16, 0, 0)

#define S_BARRIER() asm volatile("s_barrier" ::: "memory")

__device__ __forceinline__ float b2f(unsigned short u) {
  return __uint_as_float(((unsigned int)u) << 16);
}
__device__ __forceinline__ unsigned short f2bf(float f) {
  unsigned int u = __float_as_uint(f);
  u += 0x7fffu + ((u >> 16) & 1u);   // RNE
  return (unsigned short)(u >> 16);
}

// ---------------------------------------------------------------------------
// prep_a: blocks [0,8192) convert x_a,x_b -> bf16 XA (contiguous);
//         blocks [8192,11264) transpose Wqkv_a (2048x6144 f32) -> WQT bf16.
// ---------------------------------------------------------------------------
__global__ __launch_bounds__(256) void prep_a(
    const float4* __restrict__ xa, const float4* __restrict__ xb,
    uint2* __restrict__ XA, const float* __restrict__ Wq,
    unsigned short* __restrict__ WQT) {
  __shared__ unsigned short tile[64][65];
  const int bid = blockIdx.x, tid = threadIdx.x;
  if (bid < 8192) {
    const int n4each = 1048576;
    int i = bid * 256 + tid;
    if (i >= 2 * n4each) return;
    float4 v = (i < n4each) ? xa[i] : xb[i - n4each];
    uint2 o;
    o.x = (unsigned int)f2bf(v.x) | ((unsigned int)f2bf(v.y) << 16);
    o.y = (unsigned int)f2bf(v.z) | ((unsigned int)f2bf(v.w) << 16);
    XA[i] = o;
    return;
  }
  const int id = bid - 8192;               // 0..3071 = 96 x 32
  const int bc = (id % 96) * 64, br = (id / 96) * 64;
  const int c = tid & 63, r0 = tid >> 6;
  for (int r = r0; r < 64; r += 4)
    tile[r][c] = f2bf(Wq[(size_t)(br + r) * 6144 + bc + c]);
  __syncthreads();
  for (int rr = r0; rr < 64; rr += 4)
    WQT[(size_t)(bc + rr) * 2048 + br + c] = tile[c][rr];
}

// ---------------------------------------------------------------------------
// Transpose f32 (R x C) -> bf16 (C x R) (Wqkv_b path).
// ---------------------------------------------------------------------------
__global__ __launch_bounds__(256) void transpose_f32_bf16(
    const float* __restrict__ in, unsigned short* __restrict__ out,
    int R, int C) {
  __shared__ unsigned short tile[64][65];
  const int bc = blockIdx.x * 64, br = blockIdx.y * 64;
  const int c  = threadIdx.x & 63;
  const int r0 = threadIdx.x >> 6;
  for (int r = r0; r < 64; r += 4)
    tile[r][c] = f2bf(in[(size_t)(br + r) * C + bc + c]);
  __syncthreads();
  for (int rr = r0; rr < 64; rr += 4)
    out[(size_t)(bc + rr) * R + br + c] = tile[c][rr];
}

// ---------------------------------------------------------------------------
// 256x256-tile GEMM helpers.
// ---------------------------------------------------------------------------
template <int MH, int NH>
__device__ __forceinline__ void mfma_quad(v4f (&acc)[8][4], const v8s (&a)[4][2],
                                          const v8s (&b)[4][2]) {
  __builtin_amdgcn_s_setprio(1);
#pragma unroll
  for (int ks = 0; ks < 2; ++ks)
#pragma unroll
    for (int i = 0; i < 4; ++i)
#pragma unroll
      for (int j = 0; j < 2; ++j)
        acc[MH * 4 + i][NH * 2 + j] = __builtin_amdgcn_mfma_f32_16x16x32_bf16(
            a[i][ks], b[NH * 2 + j][ks], acc[MH * 4 + i][NH * 2 + j], 0, 0, 0);
  __builtin_amdgcn_s_setprio(0);
}

__device__ __forceinline__ void read_a_half(const unsigned short* lds, int base,
                                            int mh, int r, int c0, int c1,
                                            v8s (&a)[4][2]) {
#pragma unroll
  for (int i = 0; i < 4; ++i) {
    const unsigned short* ap = lds + base + (mh * 64 + i * 16 + r) * 64;
    a[i][0] = *(const v8s*)(ap + c0);
    a[i][1] = *(const v8s*)(ap + c1);
  }
}

template <int NH>
__device__ __forceinline__ void read_b_half(const unsigned short* lds, int base,
                                            int brow, int r, int c0, int c1,
                                            v8s (&b)[4][2]) {
#pragma unroll
  for (int j = 0; j < 2; ++j) {
    const unsigned short* bp = lds + base + (brow + (NH * 2 + j) * 16 + r) * 64;
    b[NH * 2 + j][0] = *(const v8s*)(bp + c0);
    b[NH * 2 + j][1] = *(const v8s*)(bp + c1);
  }
}

// ---------------------------------------------------------------------------
// gemm256: C[M,N] = A[M,K] @ BT[N,K]^T, bf16 in, bf16 out scattered to
// interleaved token rows (OSCAT 1=even, 2=odd). 8-phase counted-vmcnt
// schedule (see round-1 notes). Requires M%256==0, N%256==0, K%128==0,
// grid.x%8==0.
// ---------------------------------------------------------------------------
template <int OSCAT>
__global__ __launch_bounds__(512, 2) void gemm256(
    const unsigned short* __restrict__ A,
    const unsigned short* __restrict__ BT,
    unsigned short* __restrict__ Cb, int M, int N, int K, int NBN) {
  __shared__ __align__(16) unsigned short lds[65536];   // 128 KiB
  const int tid = threadIdx.x;

  int wg = blockIdx.x;
  const int cpx = gridDim.x >> 3;            // bijective XCD swizzle (x%8==0)
  wg = (wg & 7) * cpx + (wg >> 3);
  const int m0 = (wg / NBN) * 256, n0 = (wg % NBN) * 256;

  const int w = tid >> 6, lane = tid & 63;
  const int wm = w >> 2, wn = w & 3;         // wave tile: rows wm*128, cols wn*64
  const int r = lane & 15, q = lane >> 4;
  const int rs = r & 7;
  const int c0 = ((q ^ rs) << 3);            // swizzled ushort col, ks=0
  const int c1 = (((4 + q) ^ rs) << 3);      // ks=1
  const int brow = (wn & 1) << 6;
  const int AbaseE = (2 + wm) * 8192, BbaseE = (wn >> 1) * 8192;
  const int AbaseO = (6 + wm) * 8192, BbaseO = (4 + (wn >> 1)) * 8192;

  const int sr0 = tid >> 3, sslot = tid & 7; // staging coords
  const int NT = K >> 6, NIT = NT >> 1;

  auto stageB = [&](int p, int tt) {
    unsigned short* dst = &lds[(((tt << 2) + p) & 7) * 8192 + w * 512];
#pragma unroll
    for (int cc = 0; cc < 2; ++cc) {
      const int row = sr0 + cc * 64;
      const int g = ((sslot ^ (row & 7)) << 3);
      GL2LDS(BT + (size_t)(n0 + p * 128 + row) * K + tt * 64 + g, dst + cc * 4096);
    }
  };
  auto stageA = [&](int p, int tt) {
    unsigned short* dst = &lds[(((tt << 2) + 2 + p) & 7) * 8192 + w * 512];
#pragma unroll
    for (int cc = 0; cc < 2; ++cc) {
      const int row = sr0 + cc * 64;
      const int g = ((sslot ^ (row & 7)) << 3);
      GL2LDS(A + (size_t)(m0 + p * 128 + row) * K + tt * 64 + g, dst + cc * 4096);
    }
  };

  v4f acc[8][4] = {};
  v8s a[4][2], b[4][2];

  // prologue: B0(0) B1(0) A0(0) A1(0) | B0(1) B1(1)
  stageB(0, 0); stageB(1, 0); stageA(0, 0); stageA(1, 0);
  asm volatile("" ::: "memory");
  stageB(0, 1); stageB(1, 1);
  asm volatile("s_waitcnt vmcnt(4)" ::: "memory");   // tile 0 resident
  S_BARRIER();

  for (int it = 0; it < NIT; ++it) {
    const int t = it << 1;
    const bool more = (it + 1 < NIT);

    read_a_half(lds, AbaseE, 0, r, c0, c1, a);
    read_b_half<0>(lds, BbaseE, brow, r, c0, c1, b);
    stageA(0, t + 1);
    S_BARRIER();
    mfma_quad<0, 0>(acc, a, b);
    S_BARRIER();
    read_b_half<1>(lds, BbaseE, brow, r, c0, c1, b);
    stageA(1, t + 1);
    S_BARRIER();
    mfma_quad<0, 1>(acc, a, b);
    S_BARRIER();
    read_a_half(lds, AbaseE, 1, r, c0, c1, a);
    if (more) stageB(0, t + 2);
    S_BARRIER();
    mfma_quad<1, 0>(acc, a, b);
    S_BARRIER();
    if (more) stageB(1, t + 2);
    S_BARRIER();
    mfma_quad<1, 1>(acc, a, b);
    if (more) { asm volatile("s_waitcnt vmcnt(4)" ::: "memory"); }
    else      { asm volatile("s_waitcnt vmcnt(0)" ::: "memory"); }
    S_BARRIER();

    read_a_half(lds, AbaseO, 0, r, c0, c1, a);
    read_b_half<0>(lds, BbaseO, brow, r, c0, c1, b);
    if (more) stageA(0, t + 2);
    S_BARRIER();
    mfma_quad<0, 0>(acc, a, b);
    S_BARRIER();
    read_b_half<1>(lds, BbaseO, brow, r, c0, c1, b);
    if (more) stageA(1, t + 2);
    S_BARRIER();
    mfma_quad<0, 1>(acc, a, b);
    S_BARRIER();
    read_a_half(lds, AbaseO, 1, r, c0, c1, a);
    if (more) stageB(0, t + 3);
    S_BARRIER();
    mfma_quad<1, 0>(acc, a, b);
    S_BARRIER();
    if (more) stageB(1, t + 3);
    S_BARRIER();
    mfma_quad<1, 1>(acc, a, b);
    if (more) { asm volatile("s_waitcnt vmcnt(4)" ::: "memory"); }
    S_BARRIER();
  }

#pragma unroll
  for (int tm = 0; tm < 8; ++tm) {
    const int rowm = m0 + wm * 128 + tm * 16 + q * 4;
#pragma unroll
    for (int tn = 0; tn < 4; ++tn) {
      const int col = n0 + wn * 64 + tn * 16 + r;
#pragma unroll
      for (int p = 0; p < 4; ++p) {
        const int ar = rowm + p;
        const int orow = ((ar >> 10) << 11) + ((ar & 1023) << 1) + (OSCAT - 1);
        Cb[(size_t)orow * N + col] = f2bf(acc[tm][tn][p]);
      }
    }
  }
}

// ---------------------------------------------------------------------------
// gemm_proj2: both output projections in ONE full-machine launch.
// BM=256, BN=128, BK=64: M=4096 (both streams stacked: par = m-tile>>3),
// N=2048 -> 16x16 = 256 blocks = 1/CU. 8 waves as 4M x 2N (wave tile 64x64).
// Ring of 8 x 16KB regions, 4 slots/tile {A0,A1,B,pad}, parity alternates.
// Per tile: 3 phases (stage one half each), checkpoint vmcnt(2) at tile end
// (counted: leaves only the B staged this tile in flight). Region-overwrite
// audit: B(t+2) staged ph3(t) after B(t)'s reads (ph1,ph2) retire at the
// ph2 barrier; A*(t+2) staged ph1/ph2(t+1) after A(t)'s reads (ph1,ph3 of t).
// A rows gathered from interleaved token order; f32 output.
// ---------------------------------------------------------------------------
__global__ __launch_bounds__(512, 2) void gemm_proj2(
    const unsigned short* __restrict__ A,
    const unsigned short* __restrict__ BT0,
    const unsigned short* __restrict__ BT1,
    float* __restrict__ out, int K) {
  __shared__ __align__(16) unsigned short lds[65536];   // 128 KiB
  const int tid = threadIdx.x;

  int wg = blockIdx.x;
  const int cpx = gridDim.x >> 3;
  wg = (wg & 7) * cpx + (wg >> 3);
  const int m0 = (wg >> 4) * 256, n0 = (wg & 15) * 128;
  const int par = m0 >> 11;
  const unsigned short* __restrict__ BT = par ? BT1 : BT0;

  const int w = tid >> 6, lane = tid & 63;
  const int wm = w >> 1, wn = w & 1;         // wave tile: rows wm*64, cols wn*64
  const int r = lane & 15, q = lane >> 4;
  const int rs = r & 7;
  const int c0 = ((q ^ rs) << 3);
  const int c1 = (((4 + q) ^ rs) << 3);

  const int sr0 = tid >> 3, sslot = tid & 7;
  const int NT = K >> 6, NIT = NT >> 1;

  auto stageAh = [&](int ih, int tt) {       // A half ih (rows ih*128..+127)
    unsigned short* dst = &lds[(((tt & 1) << 2) + ih) * 8192 + w * 512];
#pragma unroll
    for (int cc = 0; cc < 2; ++cc) {
      const int row = sr0 + cc * 64;
      const int g = ((sslot ^ (row & 7)) << 3);
      const int lr = (m0 + ih * 128 + row) & 2047;
      const int gr = ((lr >> 10) << 11) + ((lr & 1023) << 1) + par;
      GL2LDS(A + (size_t)gr * K + tt * 64 + g, dst + cc * 4096);
    }
  };
  auto stageBh = [&](int tt) {               // B half (128 cols)
    unsigned short* dst = &lds[(((tt & 1) << 2) + 2) * 8192 + w * 512];
#pragma unroll
    for (int cc = 0; cc < 2; ++cc) {
      const int row = sr0 + cc * 64;
      const int g = ((sslot ^ (row & 7)) << 3);
      GL2LDS(BT + (size_t)(n0 + row) * K + tt * 64 + g, dst + cc * 4096);
    }
  };

  v4f acc[4][4] = {};
  v8s a[4][2], b[4][2];

  auto readA = [&](int ih2, int t) {         // a regs [ih2*2, ih2*2+1]
    const int base = (((t & 1) << 2) + (wm >> 1)) * 8192;
#pragma unroll
    for (int ii = 0; ii < 2; ++ii) {
      const int i = ih2 * 2 + ii;
      const unsigned short* ap = lds + base + ((wm & 1) * 64 + i * 16 + r) * 64;
      a[i][0] = *(const v8s*)(ap + c0);
      a[i][1] = *(const v8s*)(ap + c1);
    }
  };
  auto readB = [&](int jh2, int t) {
    const int base = (((t & 1) << 2) + 2) * 8192;
#pragma unroll
    for (int jj = 0; jj < 2; ++jj) {
      const int j = jh2 * 2 + jj;
      const unsigned short* bp = lds + base + (wn * 64 + j * 16 + r) * 64;
      b[j][0] = *(const v8s*)(bp + c0);
      b[j][1] = *(const v8s*)(bp + c1);
    }
  };
  auto quad = [&](int ih, int jh) {
    __builtin_amdgcn_s_setprio(1);
#pragma unroll
    for (int ks = 0; ks < 2; ++ks)
#pragma unroll
      for (int ii = 0; ii < 2; ++ii)
#pragma unroll
        for (int jj = 0; jj < 2; ++jj) {
          const int i = ih * 2 + ii, j = jh * 2 + jj;
          acc[i][j] = __builtin_amdgcn_mfma_f32_16x16x32_bf16(
              a[i][ks], b[j][ks], acc[i][j], 0, 0, 0);
        }
    __builtin_amdgcn_s_setprio(0);
  };

  // prologue: A0(0) A1(0) B(0) | B(1); tile 0 resident after vmcnt(2)
  stageAh(0, 0); stageAh(1, 0); stageBh(0);
  asm volatile("" ::: "memory");
  stageBh(1);
  asm volatile("s_waitcnt vmcnt(2)" ::: "memory");
  S_BARRIER();

  for (int u = 0; u < NIT; ++u) {
    const int t = 2 * u;
    const bool more = (u + 1 < NIT);

    // ---- even tile t: stages A0(t+1), A1(t+1), B(t+2)
    readA(0, t); readB(0, t); stageAh(0, t + 1);
    S_BARRIER(); quad(0, 0); S_BARRIER();
    readB(1, t); stageAh(1, t + 1);
    S_BARRIER(); quad(0, 1); S_BARRIER();
    readA(1, t); if (more) stageBh(t + 2);
    S_BARRIER(); quad(1, 0); quad(1, 1);
    if (more) { asm volatile("s_waitcnt vmcnt(2)" ::: "memory"); }
    else      { asm volatile("s_waitcnt vmcnt(0)" ::: "memory"); }
    S_BARRIER();

    // ---- odd tile t+1: stages A0(t+2), A1(t+2), B(t+3)
    readA(0, t + 1); readB(0, t + 1); if (more) stageAh(0, t + 2);
    S_BARRIER(); quad(0, 0); S_BARRIER();
    readB(1, t + 1); if (more) stageAh(1, t + 2);
    S_BARRIER(); quad(0, 1); S_BARRIER();
    readA(1, t + 1); if (more) stageBh(t + 3);
    S_BARRIER(); quad(1, 0); quad(1, 1);
    if (more) { asm volatile("s_waitcnt vmcnt(2)" ::: "memory"); }
    S_BARRIER();
  }

  float* Cf = out + (size_t)par * 4194304;
#pragma unroll
  for (int i = 0; i < 4; ++i) {
    const int lrow0 = (m0 & 2047) + wm * 64 + i * 16 + q * 4;
#pragma unroll
    for (int j = 0; j < 4; ++j) {
      const int col = n0 + wn * 64 + j * 16 + r;
#pragma unroll
      for (int p = 0; p < 4; ++p)
        Cf[(size_t)(lrow0 + p) * 2048 + col] = acc[i][j][p];
    }
  }
}

// ---------------------------------------------------------------------------
// rope_tv: blocks [0,4096) = RoPE Q/K (one token each, vectorized v8s);
//          blocks [4096,4608) = V transpose (vectorized global sides).
// ---------------------------------------------------------------------------
__global__ __launch_bounds__(256) void rope_tv(
    const unsigned short* __restrict__ qkv,
    const float* __restrict__ cosb, const float* __restrict__ sinb,
    unsigned short* __restrict__ Q, unsigned short* __restrict__ K,
    unsigned short* __restrict__ Vt) {
  __shared__ unsigned short tile[128][136];   // 34.8 KB (tv part only)
  const int tid = threadIdx.x;
  if (blockIdx.x < 4096) {
    const int token = blockIdx.x;            // b*2048 + t
    const int b = token >> 11, t = token & 2047;
    const unsigned short* src = qkv + (size_t)token * 6144;
    const int e0 = tid * 8, d0 = e0 & 127, h = e0 >> 7;
    const int mate0 = (d0 < 64) ? e0 + 64 : e0 - 64;
    const float sgn = (d0 < 64) ? -1.f : 1.f;
    const v8s qo = *(const v8s*)&src[e0];
    const v8s qm = *(const v8s*)&src[mate0];
    const v8s ko = *(const v8s*)&src[2048 + e0];
    const v8s km = *(const v8s*)&src[2048 + mate0];
    const float4 ca = *(const float4*)&cosb[t * 128 + d0];
    const float4 cb2 = *(const float4*)&cosb[t * 128 + d0 + 4];
    const float4 sa = *(const float4*)&sinb[t * 128 + d0];
    const float4 sb2 = *(const float4*)&sinb[t * 128 + d0 + 4];
    const float cv[8] = {ca.x, ca.y, ca.z, ca.w, cb2.x, cb2.y, cb2.z, cb2.w};
    const float sv[8] = {sa.x, sa.y, sa.z, sa.w, sb2.x, sb2.y, sb2.z, sb2.w};
    v8s qout, kout;
#pragma unroll
    for (int j = 0; j < 8; ++j) {
      qout[j] = (short)f2bf(b2f((unsigned short)qo[j]) * cv[j] +
                            b2f((unsigned short)qm[j]) * sgn * sv[j]);
      kout[j] = (short)f2bf(b2f((unsigned short)ko[j]) * cv[j] +
                            b2f((unsigned short)km[j]) * sgn * sv[j]);
    }
    const size_t off = ((size_t)(b * 16 + h) * 2048 + t) * 128 + d0;
    *(v8s*)&Q[off] = qout;
    *(v8s*)&K[off] = kout;
    return;
  }
  // ---- V transpose: (bh, tt) 128x128 tile
  const int id = blockIdx.x - 4096;
  const int bh = id >> 4, tt = id & 15;
  const int b = bh >> 4, h = bh & 15;
  const int s = tid & 15, g0 = tid >> 4;     // 16 col-groups x 16 rows/pass
#pragma unroll
  for (int ps = 0; ps < 8; ++ps) {
    const int tl = ps * 16 + g0;
    *(v8s*)&tile[tl][s * 8] =
        *(const v8s*)&qkv[((size_t)(b * 2048 + tt * 128 + tl)) * 6144 + 4096 +
                          h * 128 + s * 8];
  }
  __syncthreads();
#pragma unroll
  for (int ps = 0; ps < 8; ++ps) {
    const int dd = ps * 16 + g0;
    v8s o;
#pragma unroll
    for (int j = 0; j < 8; ++j) o[j] = (short)tile[s * 8 + j][dd];
    *(v8s*)&Vt[((size_t)(bh * 128 + dd)) * 2048 + tt * 128 + s * 8] = o;
  }
}

// ---------------------------------------------------------------------------
// attn_wpt: blocks [0,512) = flash attention (round-4 verified structure);
// blocks [512,2560) = Wproj_a/b transposes (overlap attn tail; reuse Ks LDS).
// Attn: BQ=64, BK=64, 4 waves, balanced q-tile pairing, double-buffered K/V,
// counted vmcnt(8), raw s_barrier, Q direct from global, XCD-local mapping,
// shuffle-free defer-max softmax with per-lane partial row sums.
// ---------------------------------------------------------------------------
#define SIG 0.1275174038536989f   // (1/sqrt(128)) * log2(e)

__global__ __launch_bounds__(256, 2) void attn_wpt(
    const unsigned short* __restrict__ Q, const unsigned short* __restrict__ K,
    const unsigned short* __restrict__ Vt, unsigned short* __restrict__ Y,
    const float* __restrict__ Wpa, const float* __restrict__ Wpb,
    unsigned short* __restrict__ WTa, unsigned short* __restrict__ WTb) {
  __shared__ __align__(16) unsigned short Ks[2][64 * 128];
  __shared__ __align__(16) unsigned short Vs[2][128 * 64];
  __shared__ __align__(16) unsigned short Pl[64 * 72];   // P tile, stride 72

  const int tid = threadIdx.x;
  if (blockIdx.x >= 512) {
    // ---- Wproj transpose (2048x2048 f32 -> bf16 T), z = stream
    const int id = blockIdx.x - 512;
    const int z = id >> 10, id2 = id & 1023;
    const float* in = z ? Wpb : Wpa;
    unsigned short* outp = z ? WTb : WTa;
    unsigned short* tile = &Ks[0][0];        // reuse attn LDS (64*65 <= 8192)
    const int bc = (id2 & 31) * 64, br = (id2 >> 5) * 64;
    const int c = tid & 63, r0 = tid >> 6;
    for (int r = r0; r < 64; r += 4)
      tile[r * 65 + c] = f2bf(in[(size_t)(br + r) * 2048 + bc + c]);
    __syncthreads();
    for (int rr = r0; rr < 64; rr += 4)
      outp[(size_t)(bc + rr) * 2048 + br + c] = tile[c * 65 + rr];
    return;
  }

  const int x = blockIdx.x;
  const int bh = (x & 7) * 4 + ((x >> 3) & 3);   // same-bh blocks share an XCD
  const int pr = x >> 5;
  const int w = tid >> 6, lane = tid & 63;
  const int r = lane & 15, q = lane >> 4;
  const int b = bh >> 4, h = bh & 15;
  const size_t kbase = (size_t)bh * 2048 * 128;
  const size_t vbase = (size_t)bh * 128 * 2048;
  const int vrow = lane >> 3, pc = lane & 7;

  for (int ph = 0; ph < 2; ++ph) {
    const int qt = ph ? pr : (31 - pr);

    const size_t qbase = ((size_t)bh * 2048 + qt * 64) * 128;
    v8s qf[4];
#pragma unroll
    for (int ki = 0; ki < 4; ++ki)
      qf[ki] = *(const v8s*)&Q[qbase + (size_t)(w * 16 + r) * 128 +
                               (ki * 4 + q) * 8];

    float mrun[4], lrun[4];                 // lrun = PER-LANE partial sums
    v4f O[8] = {};
#pragma unroll
    for (int p = 0; p < 4; ++p) { mrun[p] = -3.0e38f; lrun[p] = 0.f; }

    const int nkt = qt + 1;

    auto stageKV = [&](int kt, int buf) {
#pragma unroll
      for (int i = 0; i < 4; ++i) {
        const int key = w * 16 + i * 4 + q;
        const int gs = r ^ (key & 15);
        GL2LDS(K + kbase + ((size_t)kt * 64 + key) * 128 + gs * 8,
               &Ks[buf][(w * 16 + i * 4) * 128]);
      }
#pragma unroll
      for (int i = 0; i < 4; ++i) {
        const int d = w * 32 + i * 8 + vrow;
        const int gs = pc ^ (d & 7);
        GL2LDS(Vt + vbase + (size_t)d * 2048 + kt * 64 + gs * 8,
               &Vs[buf][(w * 32 + i * 8) * 64]);
      }
    };

    stageKV(0, 0);
    for (int kt = 0; kt < nkt; ++kt) {
      const int buf = kt & 1;
      if (kt + 1 < nkt) {
        stageKV(kt + 1, buf ^ 1);
        asm volatile("s_waitcnt vmcnt(8)" ::: "memory");
      } else {
        asm volatile("s_waitcnt vmcnt(0)" ::: "memory");
      }
      S_BARRIER();

      v4f S[4] = {};
      __builtin_amdgcn_s_setprio(1);
#pragma unroll
      for (int ki = 0; ki < 4; ++ki) {
        v8s kf[4];
#pragma unroll
        for (int tn = 0; tn < 4; ++tn) {
          const int key = tn * 16 + r;
          const int c = (ki * 4 + q) ^ r;
          kf[tn] = *(const v8s*)&Ks[buf][key * 128 + c * 8];
        }
#pragma unroll
        for (int tn = 0; tn < 4; ++tn)
          S[tn] = __builtin_amdgcn_mfma_f32_16x16x32_bf16(
              qf[ki], kf[tn], S[tn], 0, 0, 0);
      }
      __builtin_amdgcn_s_setprio(0);

      if (kt == qt) {
#pragma unroll
        for (int tn = 0; tn < 4; ++tn)
#pragma unroll
          for (int p = 0; p < 4; ++p) {
            const int tq = w * 16 + q * 4 + p;
            const int kg = tn * 16 + r;
            if (kg > tq) S[tn][p] = -3.0e38f;
          }
      }

      float mxp[4];
      int need = 0;
#pragma unroll
      for (int p = 0; p < 4; ++p) {
        mxp[p] = fmaxf(fmaxf(S[0][p], S[1][p]), fmaxf(S[2][p], S[3][p]));
        need |= (mxp[p] > mrun[p] + 60.0f) ? 1 : 0;
      }

      if (__builtin_expect(__any(need), 0)) {
#pragma unroll
        for (int p = 0; p < 4; ++p) {
          float mx = mxp[p];
#pragma unroll
          for (int o = 1; o < 16; o <<= 1) mx = fmaxf(mx, __shfl_xor(mx, o, 64));
          const float mnew = fmaxf(mrun[p], mx);
          const float alpha = exp2f((mrun[p] - mnew) * SIG);
          mrun[p] = mnew;
          float psum = 0.f;
#pragma unroll
          for (int tn = 0; tn < 4; ++tn) {
            const float pv = exp2f((S[tn][p] - mnew) * SIG);
            S[tn][p] = pv;
            psum += pv;
          }
          lrun[p] = lrun[p] * alpha + psum;
#pragma unroll
          for (int tn = 0; tn < 8; ++tn) O[tn][p] *= alpha;
        }
      } else {
#pragma unroll
        for (int p = 0; p < 4; ++p) {
          float psum = 0.f;
#pragma unroll
          for (int tn = 0; tn < 4; ++tn) {
            const float pv = exp2f((S[tn][p] - mrun[p]) * SIG);
            S[tn][p] = pv;
            psum += pv;
          }
          lrun[p] += psum;
        }
      }

#pragma unroll
      for (int tn = 0; tn < 4; ++tn)
#pragma unroll
        for (int p = 0; p < 4; ++p) {
          const int m = w * 16 + q * 4 + p;
          Pl[m * 72 + tn * 16 + r] = f2bf(S[tn][p]);
        }

      __builtin_amdgcn_s_setprio(1);
#pragma unroll
      for (int ki = 0; ki < 2; ++ki) {
        v8s pf, vf[8];
        const int m = w * 16 + r;
        pf = *(const v8s*)&Pl[m * 72 + (ki * 4 + q) * 8];
#pragma unroll
        for (int tn = 0; tn < 8; ++tn) {
          const int d = tn * 16 + r;
          const int c = (ki * 4 + q) ^ (d & 7);
          vf[tn] = *(const v8s*)&Vs[buf][d * 64 + c * 8];
        }
#pragma unroll
        for (int tn = 0; tn < 8; ++tn)
          O[tn] = __builtin_amdgcn_mfma_f32_16x16x32_bf16(
              pf, vf[tn], O[tn], 0, 0, 0);
      }
      __builtin_amdgcn_s_setprio(0);

      asm volatile("s_waitcnt lgkmcnt(0)" ::: "memory");
      S_BARRIER();
    }

#pragma unroll
    for (int p = 0; p < 4; ++p) {
      float s = lrun[p];
#pragma unroll
      for (int o = 1; o < 16; o <<= 1) s += __shfl_xor(s, o, 64);
      const float inv = 1.0f / s;
      const int t = qt * 64 + w * 16 + q * 4 + p;
#pragma unroll
      for (int tn = 0; tn < 8; ++tn)
        Y[((size_t)(b * 2048 + t)) * 2048 + h * 128 + tn * 16 + r] =
            f2bf(O[tn][p] * inv);
    }
  }
}

// ---------------------------------------------------------------------------
// Launch
// ---------------------------------------------------------------------------
extern "C" void kernel_launch(void* const* d_in, const int* in_sizes, int n_in,
                              void* d_out, int out_size, void* d_ws, size_t ws_size,
                              hipStream_t stream) {
  const float* x_a   = (const float*)d_in[0];
  const float* x_b   = (const float*)d_in[1];
  const float* cosb  = (const float*)d_in[2];
  const float* sinb  = (const float*)d_in[3];
  const float* Wqkv_a  = (const float*)d_in[5];
  const float* Wqkv_b  = (const float*)d_in[6];
  const float* Wproj_a = (const float*)d_in[7];
  const float* Wproj_b = (const float*)d_in[8];
  float* out = (float*)d_out;

  if (ws_size < 100663296u) return;

  char* ws = (char*)d_ws;
  unsigned short* QKVall = (unsigned short*)(ws);                // [0,48M)
  unsigned short* XA     = (unsigned short*)(ws + 50331648);     // [48,56M)
  unsigned short* WQT    = (unsigned short*)(ws + 67108864);     // [64,88M)
  unsigned short* Qb     = (unsigned short*)(ws + 50331648);     // [48,64M)
  unsigned short* Kb     = (unsigned short*)(ws + 67108864);     // [64,80M)
  unsigned short* Vtb    = (unsigned short*)(ws + 83886080);     // [80,96M)
  unsigned short* Yb     = (unsigned short*)(ws);                // [0,16M)
  unsigned short* WPT_A  = (unsigned short*)(ws + 16777216);     // [16,24M)
  unsigned short* WPT_B  = (unsigned short*)(ws + 25165824);     // [24,32M)

  // 1: x->bf16 + Wqkv_a transpose
  hipLaunchKernelGGL(prep_a, dim3(11264), dim3(256), 0, stream,
                     (const float4*)x_a, (const float4*)x_b, (uint2*)XA,
                     Wqkv_a, WQT);
  // 2: qkv GEMM stream a (even token rows)
  hipLaunchKernelGGL((gemm256<1>), dim3(192), dim3(512), 0, stream,
                     XA, WQT, QKVall, 2048, 6144, 2048, 24);
  // 3: Wqkv_b transpose
  hipLaunchKernelGGL(transpose_f32_bf16, dim3(96, 32), dim3(256), 0, stream,
                     Wqkv_b, WQT, 2048, 6144);
  // 4: qkv GEMM stream b (odd token rows)
  hipLaunchKernelGGL((gemm256<2>), dim3(192), dim3(512), 0, stream,
                     XA + (size_t)4194304, WQT, QKVall, 2048, 6144, 2048, 24);
  // 5: RoPE Q/K + V transpose
  hipLaunchKernelGGL(rope_tv, dim3(4608), dim3(256), 0, stream,
                     QKVall, cosb, sinb, Qb, Kb, Vtb);
  // 6: flash attention + Wproj transposes
  hipLaunchKernelGGL(attn_wpt, dim3(2560), dim3(256), 0, stream,
                     Qb, Kb, Vtb, Yb, Wproj_a, Wproj_b, WPT_A, WPT_B);
  // 7: both output projections, full machine
  hipLaunchKernelGGL(gemm_proj2, dim3(256), dim3(512), 0, stream,
                     Yb, WPT_A, WPT_B, out, 2048);
}